// Round 1
// baseline (1131.171 us; speedup 1.0000x reference)
//
#include <hip/hip_runtime.h>
#include <hip/hip_bf16.h>

#define B_   2
#define T_   2048
#define D_   2048
#define H_   16
#define DH_  128
#define DFF_ 8192

typedef __attribute__((ext_vector_type(8))) short bf16x8;
typedef __attribute__((ext_vector_type(4))) float f32x4;

__device__ __forceinline__ short f2bf(float f) {
    __hip_bfloat16 h = __float2bfloat16(f);
    return *reinterpret_cast<short*>(&h);
}

__device__ __forceinline__ void gload_lds16(const void* g, void* l) {
    __builtin_amdgcn_global_load_lds(
        (const __attribute__((address_space(1))) void*)g,
        (__attribute__((address_space(3))) void*)l,
        16, 0, 0);
}

__device__ __forceinline__ float gelu_tanh(float x) {
    float x3 = x * x * x;
    return 0.5f * x * (1.f + tanhf(0.7978845608028654f * (x + 0.044715f * x3)));
}

// ---------------------------------------------------------------------------
// Transpose + f32->bf16 convert:  in (K x N, f32, row-major) -> out rows
// [out_row0 .. out_row0+N) of a (R x out_ld) bf16 matrix, out[n][k] = in[k][n]
// ---------------------------------------------------------------------------
__global__ void transpose_cvt(const float* __restrict__ in, __hip_bfloat16* __restrict__ out,
                              int K, int N, int out_ld, int out_row0)
{
    __shared__ float t[32][33];
    int n0 = blockIdx.x * 32, k0 = blockIdx.y * 32;
    int tx = threadIdx.x, ty = threadIdx.y;
#pragma unroll
    for (int i = 0; i < 4; ++i)
        t[ty + i * 8][tx] = in[(size_t)(k0 + ty + i * 8) * N + n0 + tx];
    __syncthreads();
#pragma unroll
    for (int i = 0; i < 4; ++i)
        out[(size_t)(out_row0 + n0 + ty + i * 8) * out_ld + k0 + tx] =
            __float2bfloat16(t[tx][ty + i * 8]);
}

// ---------------------------------------------------------------------------
// LayerNorm: one block per row of D_=2048, out = bf16
// ---------------------------------------------------------------------------
__global__ __launch_bounds__(256) void ln_kernel(const float* __restrict__ x,
                                                 const float* __restrict__ sc,
                                                 const float* __restrict__ of,
                                                 __hip_bfloat16* __restrict__ out)
{
    int row = blockIdx.x, tid = threadIdx.x;
    const float* xr = x + (size_t)row * D_;
    float4 v0 = reinterpret_cast<const float4*>(xr)[tid * 2];
    float4 v1 = reinterpret_cast<const float4*>(xr)[tid * 2 + 1];
    float vv[8] = {v0.x, v0.y, v0.z, v0.w, v1.x, v1.y, v1.z, v1.w};
    float s = 0.f, ss = 0.f;
#pragma unroll
    for (int j = 0; j < 8; ++j) { s += vv[j]; ss += vv[j] * vv[j]; }
    for (int o = 32; o; o >>= 1) { s += __shfl_down(s, o); ss += __shfl_down(ss, o); }
    __shared__ float red[8];
    int wid = tid >> 6, lane = tid & 63;
    if (!lane) { red[wid] = s; red[4 + wid] = ss; }
    __syncthreads();
    s  = red[0] + red[1] + red[2] + red[3];
    ss = red[4] + red[5] + red[6] + red[7];
    float mean = s * (1.f / D_);
    float var  = ss * (1.f / D_) - mean * mean;
    float rstd = rsqrtf(var + 1e-5f);
    int c0 = tid * 8;
    __hip_bfloat16 ob[8];
#pragma unroll
    for (int j = 0; j < 8; ++j)
        ob[j] = __float2bfloat16((vv[j] - mean) * rstd * sc[c0 + j] + of[c0 + j]);
    *reinterpret_cast<uint4*>(out + (size_t)row * D_ + c0) = *reinterpret_cast<uint4*>(ob);
}

// ---------------------------------------------------------------------------
// GEMM: C[M x N] = epilogue(A[M x K] @ B) with B given transposed (BT: N x K),
// both bf16, fp32 accum. m97 structure: 128x128 tile, BK=32, 4 waves, each
// wave 64x64 via acc[4][4] of mfma_f32_16x16x32_bf16. LDS staged with
// global_load_lds (16B) and (row&3)<<4 XOR swizzle (8-way -> 4-way conflicts).
// EPI: 0 = bf16 out; 1 = f32 out + resid; 2 = bf16 out + bias + gelu;
//      3 = f32 out + bias + resid
// ---------------------------------------------------------------------------
template<int EPI>
__global__ __launch_bounds__(256) void gemm_bt(
    const __hip_bfloat16* __restrict__ A, const __hip_bfloat16* __restrict__ BT,
    void* __restrict__ Cout, const float* __restrict__ bias,
    const float* __restrict__ resid, int M, int N, int K)
{
    __shared__ short As[128 * 32];
    __shared__ short Bs[128 * 32];
    const int tid = threadIdx.x;
    const int wid = tid >> 6, lane = tid & 63;
    const int lo = lane & 15, hi = lane >> 4;
    const int wr = wid >> 1, wc = wid & 1;
    const int m0 = blockIdx.y * 128, n0 = blockIdx.x * 128;

    f32x4 acc[4][4] = {};
    const int ca = wid * 128 + lane;

    for (int kt = 0; kt < K; kt += 32) {
        __syncthreads();
#pragma unroll
        for (int r = 0; r < 2; ++r) {
            int c   = ca + r * 64;
            int row = c >> 2;
            int cbs = ((c & 3) * 16) ^ ((row & 3) << 4);
            gload_lds16(A  + (size_t)(m0 + row) * K + kt + (cbs >> 1),
                        &As[(wid * 128 + r * 64) * 8]);
            gload_lds16(BT + (size_t)(n0 + row) * K + kt + (cbs >> 1),
                        &Bs[(wid * 128 + r * 64) * 8]);
        }
        __syncthreads();
        bf16x8 a[4], b[4];
        const int sw = (lo & 3) << 4;
#pragma unroll
        for (int m = 0; m < 4; ++m)
            a[m] = *reinterpret_cast<const bf16x8*>(
                (const char*)As + (wr * 64 + m * 16 + lo) * 64 + ((hi * 16) ^ sw));
#pragma unroll
        for (int n = 0; n < 4; ++n)
            b[n] = *reinterpret_cast<const bf16x8*>(
                (const char*)Bs + (wc * 64 + n * 16 + lo) * 64 + ((hi * 16) ^ sw));
#pragma unroll
        for (int m = 0; m < 4; ++m)
#pragma unroll
            for (int n = 0; n < 4; ++n)
                acc[m][n] = __builtin_amdgcn_mfma_f32_16x16x32_bf16(a[m], b[n], acc[m][n], 0, 0, 0);
    }

    float* Cf = (float*)Cout;
    __hip_bfloat16* Cb = (__hip_bfloat16*)Cout;
#pragma unroll
    for (int m = 0; m < 4; ++m) {
        int rbase = m0 + wr * 64 + m * 16 + hi * 4;
#pragma unroll
        for (int n = 0; n < 4; ++n) {
            int col = n0 + wc * 64 + n * 16 + lo;
            float bv = (EPI == 2 || EPI == 3) ? bias[col] : 0.f;
#pragma unroll
            for (int i = 0; i < 4; ++i) {
                size_t idx = (size_t)(rbase + i) * N + col;
                float v = acc[m][n][i];
                if (EPI == 2 || EPI == 3) v += bv;
                if (EPI == 2) v = gelu_tanh(v);
                if (EPI == 1 || EPI == 3) v += resid[idx];
                if (EPI == 0 || EPI == 2) Cb[idx] = __float2bfloat16(v);
                else                      Cf[idx] = v;
            }
        }
    }
}

// ---------------------------------------------------------------------------
// RoPE in-place on q and k halves of qkv (B*T x 6144 bf16).
// One thread per (b, t, h, pair).  pairs: out[2p]=x1*c-x2*s, out[2p+1]=x2*c+x1*s
// ---------------------------------------------------------------------------
__global__ __launch_bounds__(256) void rope_kernel(__hip_bfloat16* __restrict__ qkv)
{
    int idx = blockIdx.x * 256 + threadIdx.x;      // < B*T*H*32 = 2097152
    int p  = idx & 31;
    int h  = (idx >> 5) & (H_ - 1);
    int bt = idx >> 9;
    int t  = bt & (T_ - 1);
    float invf = powf(10000.f, -(float)p * (1.f / 32.f));
    float fr = (float)t * invf;
    float cs = cosf(fr), sn = sinf(fr);
    size_t base = (size_t)bt * (3 * D_) + h * DH_ + 2 * p;
    float x1 = __bfloat162float(qkv[base]), x2 = __bfloat162float(qkv[base + 1]);
    qkv[base]     = __float2bfloat16(x1 * cs - x2 * sn);
    qkv[base + 1] = __float2bfloat16(x2 * cs + x1 * sn);
    size_t kb = base + D_;
    x1 = __bfloat162float(qkv[kb]); x2 = __bfloat162float(qkv[kb + 1]);
    qkv[kb]     = __float2bfloat16(x1 * cs - x2 * sn);
    qkv[kb + 1] = __float2bfloat16(x2 * cs + x1 * sn);
}

// ---------------------------------------------------------------------------
// Causal flash attention. grid = (T/64, B*H), 256 threads (4 waves).
// Wave w handles 16 q-rows (t0 = bx*64 + w*16). Per 32-wide K/V tile:
//   K staged via global_load_lds with (row&7)<<4 source pre-swizzle,
//   V reg-staged transposed (VsT[d][s]) with (d&3) swizzle,
//   QK^T via mfma (C: col=s=lane&15, row=t=(lane>>4)*4+i), online softmax in
//   fp32 with shfl_xor row-reduce, P round-trips LDS into A-fragment layout.
// ---------------------------------------------------------------------------
__global__ __launch_bounds__(256) void attn_kernel(const __hip_bfloat16* __restrict__ qkv,
                                                   __hip_bfloat16* __restrict__ ctx)
{
    constexpr int LDQ = 3 * D_;                    // 6144
    const int bh = blockIdx.y, b = bh >> 4, h = bh & 15;
    const int tq0 = blockIdx.x * 64;
    const int tid = threadIdx.x, wid = tid >> 6, lane = tid & 63;
    const int lo = lane & 15, hi = lane >> 4;
    const int t0 = tq0 + wid * 16;

    __shared__ short Ks[32 * 128];                 // swizzled K tile
    __shared__ short VsT[128 * 32];                // transposed+swizzled V tile
    __shared__ short Ps[4][16 * 56];               // per-wave P tile, 112B rows

    const __hip_bfloat16* qrow = qkv + (size_t)(b * T_ + t0 + lo) * LDQ + h * DH_;
    bf16x8 qf[4];
#pragma unroll
    for (int dk = 0; dk < 4; ++dk)
        qf[dk] = *reinterpret_cast<const bf16x8*>(qrow + dk * 32 + hi * 8);

    f32x4 octx[8] = {};
    float mreg[4] = {-1e30f, -1e30f, -1e30f, -1e30f};
    float lreg[4] = {0.f, 0.f, 0.f, 0.f};

    const size_t kvrow0 = (size_t)(b * T_) * LDQ + h * DH_;
    const int nst = (tq0 + 64) >> 5;

    for (int st = 0; st < nst; ++st) {
        const int s0 = st * 32;
        __syncthreads();
        // stage K (32 x 128 bf16), swizzled source -> linear LDS
#pragma unroll
        for (int r = 0; r < 2; ++r) {
            int c    = wid * 128 + r * 64 + lane;
            int srow = c >> 4;
            int cbs  = ((c & 15) * 16) ^ ((srow & 7) << 4);
            gload_lds16(qkv + kvrow0 + (size_t)(s0 + srow) * LDQ + D_ + (cbs >> 1),
                        &Ks[(wid * 128 + r * 64) * 8]);
        }
        // stage V transposed: VsT[d][s], swizzle s ^= (d&3)<<3
#pragma unroll
        for (int r = 0; r < 2; ++r) {
            int c = r * 256 + tid;
            int srow = c >> 4, dc = c & 15;
            bf16x8 v8 = *reinterpret_cast<const bf16x8*>(
                qkv + kvrow0 + (size_t)(s0 + srow) * LDQ + 2 * D_ + dc * 8);
#pragma unroll
            for (int j = 0; j < 8; ++j)
                VsT[(dc * 8 + j) * 32 + (srow ^ ((j & 3) << 3))] = v8[j];
        }
        __syncthreads();

        // S = Q K^T  (two 16-col fragments)
        f32x4 sfr[2] = {};
#pragma unroll
        for (int f = 0; f < 2; ++f) {
            int srow = f * 16 + lo;
            int sw = (srow & 7) << 4;
#pragma unroll
            for (int dk = 0; dk < 4; ++dk) {
                bf16x8 kf = *reinterpret_cast<const bf16x8*>(
                    (const char*)Ks + srow * 256 + ((dk * 64 + hi * 16) ^ sw));
                sfr[f] = __builtin_amdgcn_mfma_f32_16x16x32_bf16(qf[dk], kf, sfr[f], 0, 0, 0);
            }
        }
        // scale + causal mask
        const float qsc = 0.08838834764831845f;   // 1/sqrt(128)
#pragma unroll
        for (int f = 0; f < 2; ++f)
#pragma unroll
            for (int i = 0; i < 4; ++i) {
                float v = sfr[f][i] * qsc;
                if (s0 + f * 16 + lo > t0 + hi * 4 + i) v = -1e30f;
                sfr[f][i] = v;
            }
        // online softmax (rows live across the 16 lanes of each hi-group)
        float ps[4];
#pragma unroll
        for (int i = 0; i < 4; ++i) {
            float v = fmaxf(sfr[0][i], sfr[1][i]);
            v = fmaxf(v, __shfl_xor(v, 1));
            v = fmaxf(v, __shfl_xor(v, 2));
            v = fmaxf(v, __shfl_xor(v, 4));
            v = fmaxf(v, __shfl_xor(v, 8));
            float mn = fmaxf(mreg[i], v);
            ps[i] = __expf(mreg[i] - mn);
            mreg[i] = mn;
        }
#pragma unroll
        for (int f = 0; f < 2; ++f)
#pragma unroll
            for (int i = 0; i < 4; ++i)
                sfr[f][i] = __expf(sfr[f][i] - mreg[i]);
#pragma unroll
        for (int i = 0; i < 4; ++i) {
            float v = sfr[0][i] + sfr[1][i];
            v += __shfl_xor(v, 1); v += __shfl_xor(v, 2);
            v += __shfl_xor(v, 4); v += __shfl_xor(v, 8);
            lreg[i] = lreg[i] * ps[i] + v;
        }
#pragma unroll
        for (int f8 = 0; f8 < 8; ++f8)
#pragma unroll
            for (int i = 0; i < 4; ++i)
                octx[f8][i] *= ps[i];

        // P (C layout) -> LDS -> A-fragment layout
        short* pw = &Ps[wid][0];
#pragma unroll
        for (int f = 0; f < 2; ++f)
#pragma unroll
            for (int i = 0; i < 4; ++i)
                pw[(hi * 4 + i) * 56 + f * 16 + lo] = f2bf(sfr[f][i]);
        asm volatile("s_waitcnt lgkmcnt(0)" ::: "memory");
        bf16x8 pa = *reinterpret_cast<const bf16x8*>((const char*)pw + lo * 112 + hi * 16);

        // ctx += P @ V
#pragma unroll
        for (int f8 = 0; f8 < 8; ++f8) {
            bf16x8 vf = *reinterpret_cast<const bf16x8*>(
                (const char*)VsT + (f8 * 16 + lo) * 64 + ((hi * 16) ^ ((lo & 3) << 4)));
            octx[f8] = __builtin_amdgcn_mfma_f32_16x16x32_bf16(pa, vf, octx[f8], 0, 0, 0);
        }
    }

    // normalize + write ctx (b*T+t, h*128+d), bf16
#pragma unroll
    for (int i = 0; i < 4; ++i) {
        float inv = 1.f / lreg[i];
        size_t rb = (size_t)(b * T_ + t0 + hi * 4 + i) * D_ + h * DH_;
#pragma unroll
        for (int f8 = 0; f8 < 8; ++f8)
            ctx[rb + f8 * 16 + lo] = __float2bfloat16(octx[f8][i] * inv);
    }
}

// ---------------------------------------------------------------------------
extern "C" void kernel_launch(void* const* d_in, const int* in_sizes, int n_in,
                              void* d_out, int out_size, void* d_ws, size_t ws_size,
                              hipStream_t stream)
{
    (void)in_sizes; (void)n_in; (void)out_size; (void)ws_size;
    const float* x   = (const float*)d_in[0];
    const float* lns = (const float*)d_in[1];
    const float* lno = (const float*)d_in[2];
    const float* wq  = (const float*)d_in[3];
    const float* wk  = (const float*)d_in[4];
    const float* wv  = (const float*)d_in[5];
    const float* wo  = (const float*)d_in[6];
    const float* w1  = (const float*)d_in[7];
    const float* b1  = (const float*)d_in[8];
    const float* w2  = (const float*)d_in[9];
    const float* b2  = (const float*)d_in[10];
    float* out = (float*)d_out;

    // workspace layout (bytes). total = 218,103,808
    char* ws = (char*)d_ws;
    __hip_bfloat16* wqkvT = (__hip_bfloat16*)(ws);                 // 6144x2048 bf16
    __hip_bfloat16* woT   = (__hip_bfloat16*)(ws + 25165824);      // 2048x2048
    __hip_bfloat16* w1T   = (__hip_bfloat16*)(ws + 33554432);      // 8192x2048
    __hip_bfloat16* w2T   = (__hip_bfloat16*)(ws + 67108864);      // 2048x8192
    __hip_bfloat16* xn    = (__hip_bfloat16*)(ws + 100663296);     // 4096x2048 (xn / xn2)
    __hip_bfloat16* qkv   = (__hip_bfloat16*)(ws + 117440512);     // 4096x6144
    __hip_bfloat16* hbuf  = qkv;                                   // 4096x8192 (aliases qkv+ctx)
    __hip_bfloat16* ctx   = (__hip_bfloat16*)(ws + 167772160);     // 4096x2048
    float*          x1    = (float*)(ws + 184549376);              // 4096x2048 f32

    dim3 tb(32, 8);
    transpose_cvt<<<dim3(64, 64),  tb, 0, stream>>>(wq, wqkvT, 2048, 2048, 2048, 0);
    transpose_cvt<<<dim3(64, 64),  tb, 0, stream>>>(wk, wqkvT, 2048, 2048, 2048, 2048);
    transpose_cvt<<<dim3(64, 64),  tb, 0, stream>>>(wv, wqkvT, 2048, 2048, 2048, 4096);
    transpose_cvt<<<dim3(64, 64),  tb, 0, stream>>>(wo, woT,   2048, 2048, 2048, 0);
    transpose_cvt<<<dim3(256, 64), tb, 0, stream>>>(w1, w1T,   2048, 8192, 2048, 0);
    transpose_cvt<<<dim3(64, 256), tb, 0, stream>>>(w2, w2T,   8192, 2048, 8192, 0);

    ln_kernel<<<4096, 256, 0, stream>>>(x, lns, lno, xn);
    gemm_bt<0><<<dim3(48, 32), 256, 0, stream>>>(xn, wqkvT, qkv, nullptr, nullptr, 4096, 6144, 2048);
    rope_kernel<<<8192, 256, 0, stream>>>(qkv);
    attn_kernel<<<dim3(32, 32), 256, 0, stream>>>(qkv, ctx);
    gemm_bt<1><<<dim3(16, 32), 256, 0, stream>>>(ctx, woT, x1, nullptr, x, 4096, 2048, 2048);
    ln_kernel<<<4096, 256, 0, stream>>>(x1, lns, lno, xn);
    gemm_bt<2><<<dim3(64, 32), 256, 0, stream>>>(xn, w1T, hbuf, b1, nullptr, 4096, 8192, 2048);
    gemm_bt<3><<<dim3(16, 32), 256, 0, stream>>>(hbuf, w2T, out, b2, x1, 4096, 2048, 8192);
}

// Round 2
// 814.442 us; speedup vs baseline: 1.3889x; 1.3889x over previous
//
#include <hip/hip_runtime.h>
#include <hip/hip_bf16.h>

#define B_   2
#define T_   2048
#define D_   2048
#define H_   16
#define DH_  128
#define DFF_ 8192

typedef __attribute__((ext_vector_type(8))) short bf16x8;
typedef __attribute__((ext_vector_type(4))) float f32x4;

__device__ __forceinline__ short f2bf(float f) {
    __hip_bfloat16 h = __float2bfloat16(f);
    return *reinterpret_cast<short*>(&h);
}

__device__ __forceinline__ void gload_lds16(const void* g, void* l) {
    __builtin_amdgcn_global_load_lds(
        (const __attribute__((address_space(1))) void*)g,
        (__attribute__((address_space(3))) void*)l,
        16, 0, 0);
}

__device__ __forceinline__ float gelu_tanh(float x) {
    float x3 = x * x * x;
    return 0.5f * x * (1.f + tanhf(0.7978845608028654f * (x + 0.044715f * x3)));
}

// ---------------------------------------------------------------------------
// Transpose + f32->bf16 convert, vectorized: tile 32(k) x 64(n), 256 threads.
// float4 loads, uint4 (8 bf16) stores.
// ---------------------------------------------------------------------------
__global__ __launch_bounds__(256) void transpose_cvt(const float* __restrict__ in,
                                                     __hip_bfloat16* __restrict__ out,
                                                     int K, int N, int out_ld, int out_row0)
{
    __shared__ float t[32][65];
    const int n0 = blockIdx.x * 64, k0 = blockIdx.y * 32;
    const int tid = threadIdx.x;
    // load: 32 rows x 64 cols of f32
    {
        int kr = tid >> 4;            // 0..15
        int nc = (tid & 15) * 4;      // 0..60
        const float* src = in + (size_t)(k0 + kr) * N + n0 + nc;
        float4 a = *reinterpret_cast<const float4*>(src);
        float4 b = *reinterpret_cast<const float4*>(src + (size_t)16 * N);
        t[kr][nc] = a.x; t[kr][nc + 1] = a.y; t[kr][nc + 2] = a.z; t[kr][nc + 3] = a.w;
        t[kr + 16][nc] = b.x; t[kr + 16][nc + 1] = b.y; t[kr + 16][nc + 2] = b.z; t[kr + 16][nc + 3] = b.w;
    }
    __syncthreads();
    // store: 64 rows (n) x 32 cols (k), 8 bf16 per thread
    {
        int n  = tid >> 2;            // 0..63
        int kc = (tid & 3) * 8;       // 0..24
        __hip_bfloat16 ob[8];
#pragma unroll
        for (int j = 0; j < 8; ++j) ob[j] = __float2bfloat16(t[kc + j][n]);
        *reinterpret_cast<uint4*>(out + (size_t)(out_row0 + n0 + n) * out_ld + k0 + kc) =
            *reinterpret_cast<uint4*>(ob);
    }
}

// ---------------------------------------------------------------------------
// LayerNorm: one block per row of D_=2048, out = bf16
// ---------------------------------------------------------------------------
__global__ __launch_bounds__(256) void ln_kernel(const float* __restrict__ x,
                                                 const float* __restrict__ sc,
                                                 const float* __restrict__ of,
                                                 __hip_bfloat16* __restrict__ out)
{
    int row = blockIdx.x, tid = threadIdx.x;
    const float* xr = x + (size_t)row * D_;
    float4 v0 = reinterpret_cast<const float4*>(xr)[tid * 2];
    float4 v1 = reinterpret_cast<const float4*>(xr)[tid * 2 + 1];
    float vv[8] = {v0.x, v0.y, v0.z, v0.w, v1.x, v1.y, v1.z, v1.w};
    float s = 0.f, ss = 0.f;
#pragma unroll
    for (int j = 0; j < 8; ++j) { s += vv[j]; ss += vv[j] * vv[j]; }
    for (int o = 32; o; o >>= 1) { s += __shfl_down(s, o); ss += __shfl_down(ss, o); }
    __shared__ float red[8];
    int wid = tid >> 6, lane = tid & 63;
    if (!lane) { red[wid] = s; red[4 + wid] = ss; }
    __syncthreads();
    s  = red[0] + red[1] + red[2] + red[3];
    ss = red[4] + red[5] + red[6] + red[7];
    float mean = s * (1.f / D_);
    float var  = ss * (1.f / D_) - mean * mean;
    float rstd = rsqrtf(var + 1e-5f);
    int c0 = tid * 8;
    __hip_bfloat16 ob[8];
#pragma unroll
    for (int j = 0; j < 8; ++j)
        ob[j] = __float2bfloat16((vv[j] - mean) * rstd * sc[c0 + j] + of[c0 + j]);
    *reinterpret_cast<uint4*>(out + (size_t)row * D_ + c0) = *reinterpret_cast<uint4*>(ob);
}

// ---------------------------------------------------------------------------
// GEMM (m97 structure) — unchanged from round 1.
// ---------------------------------------------------------------------------
template<int EPI>
__global__ __launch_bounds__(256) void gemm_bt(
    const __hip_bfloat16* __restrict__ A, const __hip_bfloat16* __restrict__ BT,
    void* __restrict__ Cout, const float* __restrict__ bias,
    const float* __restrict__ resid, int M, int N, int K)
{
    __shared__ short As[128 * 32];
    __shared__ short Bs[128 * 32];
    const int tid = threadIdx.x;
    const int wid = tid >> 6, lane = tid & 63;
    const int lo = lane & 15, hi = lane >> 4;
    const int wr = wid >> 1, wc = wid & 1;
    const int m0 = blockIdx.y * 128, n0 = blockIdx.x * 128;

    f32x4 acc[4][4] = {};
    const int ca = wid * 128 + lane;

    for (int kt = 0; kt < K; kt += 32) {
        __syncthreads();
#pragma unroll
        for (int r = 0; r < 2; ++r) {
            int c   = ca + r * 64;
            int row = c >> 2;
            int cbs = ((c & 3) * 16) ^ ((row & 3) << 4);
            gload_lds16(A  + (size_t)(m0 + row) * K + kt + (cbs >> 1),
                        &As[(wid * 128 + r * 64) * 8]);
            gload_lds16(BT + (size_t)(n0 + row) * K + kt + (cbs >> 1),
                        &Bs[(wid * 128 + r * 64) * 8]);
        }
        __syncthreads();
        bf16x8 a[4], b[4];
        const int sw = (lo & 3) << 4;
#pragma unroll
        for (int m = 0; m < 4; ++m)
            a[m] = *reinterpret_cast<const bf16x8*>(
                (const char*)As + (wr * 64 + m * 16 + lo) * 64 + ((hi * 16) ^ sw));
#pragma unroll
        for (int n = 0; n < 4; ++n)
            b[n] = *reinterpret_cast<const bf16x8*>(
                (const char*)Bs + (wc * 64 + n * 16 + lo) * 64 + ((hi * 16) ^ sw));
        __builtin_amdgcn_s_setprio(1);
#pragma unroll
        for (int m = 0; m < 4; ++m)
#pragma unroll
            for (int n = 0; n < 4; ++n)
                acc[m][n] = __builtin_amdgcn_mfma_f32_16x16x32_bf16(a[m], b[n], acc[m][n], 0, 0, 0);
        __builtin_amdgcn_s_setprio(0);
    }

    float* Cf = (float*)Cout;
    __hip_bfloat16* Cb = (__hip_bfloat16*)Cout;
#pragma unroll
    for (int m = 0; m < 4; ++m) {
        int rbase = m0 + wr * 64 + m * 16 + hi * 4;
#pragma unroll
        for (int n = 0; n < 4; ++n) {
            int col = n0 + wc * 64 + n * 16 + lo;
            float bv = (EPI == 2 || EPI == 3) ? bias[col] : 0.f;
#pragma unroll
            for (int i = 0; i < 4; ++i) {
                size_t idx = (size_t)(rbase + i) * N + col;
                float v = acc[m][n][i];
                if (EPI == 2 || EPI == 3) v += bv;
                if (EPI == 2) v = gelu_tanh(v);
                if (EPI == 1 || EPI == 3) v += resid[idx];
                if (EPI == 0 || EPI == 2) Cb[idx] = __float2bfloat16(v);
                else                      Cf[idx] = v;
            }
        }
    }
}

// ---------------------------------------------------------------------------
// RoPE in-place on q,k halves of qkv. u32 pair loads, exp2f + __sincosf.
// ---------------------------------------------------------------------------
__global__ __launch_bounds__(256) void rope_kernel(__hip_bfloat16* __restrict__ qkv)
{
    int idx = blockIdx.x * 256 + threadIdx.x;      // < B*T*H*32 = 2097152
    int p  = idx & 31;
    int h  = (idx >> 5) & (H_ - 1);
    int bt = idx >> 9;
    int t  = bt & (T_ - 1);
    // 10000^(-p/32) = exp2(-p * log2(10000)/32)
    float invf = exp2f((float)p * -0.4152410118609203f);
    float fr = (float)t * invf;
    float cs, sn;
    __sincosf(fr, &sn, &cs);
    size_t base = (size_t)bt * (3 * D_) + h * DH_ + 2 * p;
#pragma unroll
    for (int qk = 0; qk < 2; ++qk) {
        uint* pp = reinterpret_cast<uint*>(qkv + base + qk * D_);
        uint u = *pp;
        float x1 = __uint_as_float(u << 16);
        float x2 = __uint_as_float(u & 0xffff0000u);
        short r0 = f2bf(x1 * cs - x2 * sn);
        short r1 = f2bf(x2 * cs + x1 * sn);
        *pp = ((uint)(unsigned short)r0) | (((uint)(unsigned short)r1) << 16);
    }
}

// ---------------------------------------------------------------------------
// Causal flash attention v2. grid = (32, 32) remapped; 256 threads (4 waves),
// wave = 16 q-rows, KVBLK = 64.
//   K: 64x128 LDS, gload_lds with 16B-block XOR source swizzle (row&7)<<4.
//   V^T: VsT[d][s] stride 68, scatter-write with s ^= (d>>3)<<2 swizzle
//        (write-side conflict-free).
//   sigma k->s permutation: frag elem k=hi*8+e maps to s=ks*32+hi*4+e (e<4)
//   or s=ks*32+16+hi*4+(e-4); applied identically to P(A) and V^T(B) reads
//   so both are plain aligned ds_read_b64 pairs.
// ---------------------------------------------------------------------------
__global__ __launch_bounds__(256) void attn_kernel(const __hip_bfloat16* __restrict__ qkv,
                                                   __hip_bfloat16* __restrict__ ctx)
{
    constexpr int LDQ = 3 * D_;                    // 6144
    constexpr int SV  = 68;                        // VsT row stride (shorts)
    constexpr int SP  = 68;                        // Ps row stride (shorts)

    // flatten grid; XCD-chunk swizzle (8 XCDs x 128 blocks) + reverse bx for
    // load balance (largest causal blocks dispatched first within each XCD)
    int idx = blockIdx.y * 32 + blockIdx.x;        // 0..1023
    int swz = (idx & 7) * 128 + (idx >> 3);
    const int bh  = swz >> 5;                      // 4 consecutive bh per XCD
    const int bxr = 31 - (swz & 31);
    const int b = bh >> 4, h = bh & 15;
    const int tq0 = bxr * 64;

    const int tid = threadIdx.x, wid = tid >> 6, lane = tid & 63;
    const int lo = lane & 15, hi = lane >> 4;
    const int t0 = tq0 + wid * 16;

    __shared__ short Ks[64 * 128];                 // 16 KB
    __shared__ short VsT[128 * SV];                // 17 KB
    __shared__ short Ps[4][16 * SP];               // 8.5 KB

    const __hip_bfloat16* qrow = qkv + (size_t)(b * T_ + t0 + lo) * LDQ + h * DH_;
    bf16x8 qf[4];
#pragma unroll
    for (int dk = 0; dk < 4; ++dk)
        qf[dk] = *reinterpret_cast<const bf16x8*>(qrow + dk * 32 + hi * 8);

    f32x4 octx[8] = {};
    float mreg[4] = {-1e30f, -1e30f, -1e30f, -1e30f};
    float lreg[4] = {0.f, 0.f, 0.f, 0.f};

    const size_t kvrow0 = (size_t)(b * T_) * LDQ + h * DH_;
    const int nst = bxr + 1;

    for (int st = 0; st < nst; ++st) {
        const int s0 = st * 64;
        __syncthreads();
        // ---- stage K (64 x 128): 1024 16B chunks, 4 per thread
#pragma unroll
        for (int i = 0; i < 4; ++i) {
            int c    = wid * 256 + i * 64 + lane;
            int srow = c >> 4;
            int cbs  = ((c & 15) * 16) ^ ((srow & 7) << 4);
            gload_lds16(qkv + kvrow0 + (size_t)(s0 + srow) * LDQ + D_ + (cbs >> 1),
                        &Ks[(wid * 256 + i * 64) * 8]);
        }
        // ---- stage V^T (scatter, conflict-free via stride 68 + XOR swizzle)
#pragma unroll
        for (int it = 0; it < 4; ++it) {
            int c = it * 256 + tid;                // 0..1023
            int s = c >> 4, dc = c & 15;
            bf16x8 v8 = *reinterpret_cast<const bf16x8*>(
                qkv + kvrow0 + (size_t)(s0 + s) * LDQ + 2 * D_ + dc * 8);
            int sswz = s ^ ((dc & 15) << 2);
            short* dst = &VsT[(dc * 8) * SV + sswz];
#pragma unroll
            for (int j = 0; j < 8; ++j)
                dst[j * SV] = v8[j];
        }
        __syncthreads();

        // ---- S = Q K^T : 4 col-fragments x 4 k-steps
        f32x4 sfr[4] = {};
        __builtin_amdgcn_s_setprio(1);
#pragma unroll
        for (int f = 0; f < 4; ++f) {
            int srow = f * 16 + lo;
            int sw = (srow & 7) << 4;
#pragma unroll
            for (int dk = 0; dk < 4; ++dk) {
                bf16x8 kf = *reinterpret_cast<const bf16x8*>(
                    (const char*)Ks + srow * 256 + ((dk * 64 + hi * 16) ^ sw));
                sfr[f] = __builtin_amdgcn_mfma_f32_16x16x32_bf16(qf[dk], kf, sfr[f], 0, 0, 0);
            }
        }
        __builtin_amdgcn_s_setprio(0);

        // ---- scale (+ causal mask on the diagonal tile only)
        const float qsc = 0.08838834764831845f;    // 1/sqrt(128)
#pragma unroll
        for (int f = 0; f < 4; ++f)
#pragma unroll
            for (int i = 0; i < 4; ++i)
                sfr[f][i] *= qsc;
        if (st == nst - 1) {
#pragma unroll
            for (int f = 0; f < 4; ++f)
#pragma unroll
                for (int i = 0; i < 4; ++i)
                    if (s0 + f * 16 + lo > t0 + hi * 4 + i) sfr[f][i] = -1e30f;
        }

        // ---- online softmax (rows across the 16 lanes of each hi-group)
        float ps[4];
#pragma unroll
        for (int i = 0; i < 4; ++i) {
            float v = fmaxf(fmaxf(sfr[0][i], sfr[1][i]), fmaxf(sfr[2][i], sfr[3][i]));
            v = fmaxf(v, __shfl_xor(v, 1));
            v = fmaxf(v, __shfl_xor(v, 2));
            v = fmaxf(v, __shfl_xor(v, 4));
            v = fmaxf(v, __shfl_xor(v, 8));
            float mn = fmaxf(mreg[i], v);
            ps[i] = __expf(mreg[i] - mn);
            mreg[i] = mn;
        }
#pragma unroll
        for (int f = 0; f < 4; ++f)
#pragma unroll
            for (int i = 0; i < 4; ++i)
                sfr[f][i] = __expf(sfr[f][i] - mreg[i]);
#pragma unroll
        for (int i = 0; i < 4; ++i) {
            float v = sfr[0][i] + sfr[1][i] + sfr[2][i] + sfr[3][i];
            v += __shfl_xor(v, 1); v += __shfl_xor(v, 2);
            v += __shfl_xor(v, 4); v += __shfl_xor(v, 8);
            lreg[i] = lreg[i] * ps[i] + v;
        }
#pragma unroll
        for (int f8 = 0; f8 < 8; ++f8)
#pragma unroll
            for (int i = 0; i < 4; ++i)
                octx[f8][i] *= ps[i];

        // ---- P (C layout) -> per-wave LDS tile [t][s]
        short* pw = &Ps[wid][0];
#pragma unroll
        for (int f = 0; f < 4; ++f)
#pragma unroll
            for (int i = 0; i < 4; ++i)
                pw[(hi * 4 + i) * SP + f * 16 + lo] = f2bf(sfr[f][i]);
        asm volatile("s_waitcnt lgkmcnt(0)" ::: "memory");
        __builtin_amdgcn_sched_barrier(0);

        // ---- ctx += P @ V  (2 k-steps of 32 s, sigma-permuted b64 reads)
#pragma unroll
        for (int ks = 0; ks < 2; ++ks) {
            union { bf16x8 v; uint2 u[2]; } pa;
            pa.u[0] = *reinterpret_cast<const uint2*>(pw + lo * SP + ks * 32 + hi * 4);
            pa.u[1] = *reinterpret_cast<const uint2*>(pw + lo * SP + ks * 32 + 16 + hi * 4);
            __builtin_amdgcn_s_setprio(1);
#pragma unroll
            for (int f8 = 0; f8 < 8; ++f8) {
                int d = f8 * 16 + lo;
                int sw2 = ((d >> 3) & 15) << 2;
                const short* vr = &VsT[d * SV];
                union { bf16x8 v; uint2 u[2]; } vb;
                vb.u[0] = *reinterpret_cast<const uint2*>(vr + ((ks * 32 + hi * 4) ^ sw2));
                vb.u[1] = *reinterpret_cast<const uint2*>(vr + ((ks * 32 + 16 + hi * 4) ^ sw2));
                octx[f8] = __builtin_amdgcn_mfma_f32_16x16x32_bf16(pa.v, vb.v, octx[f8], 0, 0, 0);
            }
            __builtin_amdgcn_s_setprio(0);
        }
    }

    // ---- normalize + write ctx
#pragma unroll
    for (int i = 0; i < 4; ++i) {
        float inv = 1.f / lreg[i];
        size_t rb = (size_t)(b * T_ + t0 + hi * 4 + i) * D_ + h * DH_;
#pragma unroll
        for (int f8 = 0; f8 < 8; ++f8)
            ctx[rb + f8 * 16 + lo] = __float2bfloat16(octx[f8][i] * inv);
    }
}

// ---------------------------------------------------------------------------
extern "C" void kernel_launch(void* const* d_in, const int* in_sizes, int n_in,
                              void* d_out, int out_size, void* d_ws, size_t ws_size,
                              hipStream_t stream)
{
    (void)in_sizes; (void)n_in; (void)out_size; (void)ws_size;
    const float* x   = (const float*)d_in[0];
    const float* lns = (const float*)d_in[1];
    const float* lno = (const float*)d_in[2];
    const float* wq  = (const float*)d_in[3];
    const float* wk  = (const float*)d_in[4];
    const float* wv  = (const float*)d_in[5];
    const float* wo  = (const float*)d_in[6];
    const float* w1  = (const float*)d_in[7];
    const float* b1  = (const float*)d_in[8];
    const float* w2  = (const float*)d_in[9];
    const float* b2  = (const float*)d_in[10];
    float* out = (float*)d_out;

    char* ws = (char*)d_ws;
    __hip_bfloat16* wqkvT = (__hip_bfloat16*)(ws);                 // 6144x2048 bf16
    __hip_bfloat16* woT   = (__hip_bfloat16*)(ws + 25165824);      // 2048x2048
    __hip_bfloat16* w1T   = (__hip_bfloat16*)(ws + 33554432);      // 8192x2048
    __hip_bfloat16* w2T   = (__hip_bfloat16*)(ws + 67108864);      // 2048x8192
    __hip_bfloat16* xn    = (__hip_bfloat16*)(ws + 100663296);     // 4096x2048 (xn / xn2)
    __hip_bfloat16* qkv   = (__hip_bfloat16*)(ws + 117440512);     // 4096x6144
    __hip_bfloat16* hbuf  = qkv;                                   // 4096x8192 (aliases qkv+ctx)
    __hip_bfloat16* ctx   = (__hip_bfloat16*)(ws + 167772160);     // 4096x2048
    float*          x1    = (float*)(ws + 184549376);              // 4096x2048 f32

    transpose_cvt<<<dim3(32, 64),  256, 0, stream>>>(wq, wqkvT, 2048, 2048, 2048, 0);
    transpose_cvt<<<dim3(32, 64),  256, 0, stream>>>(wk, wqkvT, 2048, 2048, 2048, 2048);
    transpose_cvt<<<dim3(32, 64),  256, 0, stream>>>(wv, wqkvT, 2048, 2048, 2048, 4096);
    transpose_cvt<<<dim3(32, 64),  256, 0, stream>>>(wo, woT,   2048, 2048, 2048, 0);
    transpose_cvt<<<dim3(128, 64), 256, 0, stream>>>(w1, w1T,   2048, 8192, 2048, 0);
    transpose_cvt<<<dim3(32, 256), 256, 0, stream>>>(w2, w2T,   8192, 2048, 8192, 0);

    ln_kernel<<<4096, 256, 0, stream>>>(x, lns, lno, xn);
    gemm_bt<0><<<dim3(48, 32), 256, 0, stream>>>(xn, wqkvT, qkv, nullptr, nullptr, 4096, 6144, 2048);
    rope_kernel<<<8192, 256, 0, stream>>>(qkv);
    attn_kernel<<<dim3(32, 32), 256, 0, stream>>>(qkv, ctx);
    gemm_bt<1><<<dim3(16, 32), 256, 0, stream>>>(ctx, woT, x1, nullptr, x, 4096, 2048, 2048);
    ln_kernel<<<4096, 256, 0, stream>>>(x1, lns, lno, xn);
    gemm_bt<2><<<dim3(64, 32), 256, 0, stream>>>(xn, w1T, hbuf, b1, nullptr, 4096, 8192, 2048);
    gemm_bt<3><<<dim3(16, 32), 256, 0, stream>>>(hbuf, w2T, out, b2, x1, 4096, 2048, 8192);
}